// Round 5
// baseline (569.372 us; speedup 1.0000x reference)
//
#include <hip/hip_runtime.h>
#include <math.h>

#define NS   3072
#define KT   64
#define CC   128
#define TDIM 100
#define TGN  98304
#define TH   32
#define CH   512
#define PS   136   // LNzb/Gb bf16 stride (272 B rows, 16B-aligned)
#define PSA  136   // Ab half-K stride
#define PSK  72    // LNz1T stride (144 B)
#define PSH  40    // G2T stride (80 B)

typedef __attribute__((ext_vector_type(8))) short bf16x8;
typedef __attribute__((ext_vector_type(4))) float f32x4;

__device__ __forceinline__ unsigned short f2bf(float f) {
    unsigned int u = __float_as_uint(f);
    return (unsigned short)((u + 0x7FFFu + ((u >> 16) & 1u)) >> 16);   // RNE
}
__device__ __forceinline__ float fast_exp2(float x) {
    float r; asm("v_exp_f32 %0, %1" : "=v"(r) : "v"(x)); return r;
}
__device__ __forceinline__ float fast_rcp(float x) {
    float r; asm("v_rcp_f32 %0, %1" : "=v"(r) : "v"(x)); return r;
}
__device__ __forceinline__ float fast_cos2pi(float rev) {   // cos(2*pi*rev)
    float f = rev - floorf(rev);
    float r; asm("v_cos_f32 %0, %1" : "=v"(r) : "v"(f)); return r;
}
__device__ __forceinline__ unsigned int pk_bf16(float lo, float hi) {
    unsigned int r; asm("v_cvt_pk_bf16_f32 %0, %1, %2" : "=v"(r) : "v"(lo), "v"(hi)); return r;
}
__device__ __forceinline__ float gelu_f(float x) {
    float p = x * x;
    float e = fast_exp2(-x * fmaf(p, 0.1029436f, 2.3022082f));
    return x * fast_rcp(1.0f + e);
}

// ---- single prep kernel: tiled weight transposes + small transposes + seg bounds
__global__ __launch_bounds__(256)
void gm_prep(const float* __restrict__ cW1, const float* __restrict__ cW2,
             const float* __restrict__ proj_W,
             const float* __restrict__ tW1, const float* __restrict__ tW2,
             const int*   __restrict__ tg_seg,
             unsigned short* __restrict__ cW1Tb, unsigned short* __restrict__ cW2Tb,
             unsigned short* __restrict__ projWTb,
             unsigned short* __restrict__ tW1Tb, unsigned short* __restrict__ tW2Tb,
             int* __restrict__ seg_lo)
{
    __shared__ float tile[32][33];
    const int bid = blockIdx.x;
    if (bid >= 288) {   // small path: tW1T, tW2T, seg_lo
        int e = (bid - 288) * 256 + threadIdx.x;   // 0..11519
        if (e < 4096) {           // tW1T[l][h][k]
            int l = e >> 11, rem = e & 2047, h = rem >> 6, k = rem & 63;
            tW1Tb[e] = f2bf(tW1[(l * KT + k) * TH + h]);
        } else if (e < 8192) {    // tW2T[l][k][h]
            int e2 = e - 4096, l = e2 >> 11, rem = e2 & 2047, k = rem >> 5, h = rem & 31;
            tW2Tb[e2] = f2bf(tW2[(l * TH + h) * KT + k]);
        } else if (e < 8192 + 3073) {  // seg_lo[n] = lower_bound(tg_seg, n)
            int nn = e - 8192;
            int a = 0, b = TGN;
            while (a < b) { int mm = (a + b) >> 1; if (tg_seg[mm] < nn) a = mm + 1; else b = mm; }
            seg_lo[nn] = a;
        }
        return;
    }
    const float* src; unsigned short* dst;
    int R, Cs, oC, tr, tc;
    if (bid < 128) {            // cW1 [l][128][512] -> [l][512][128]
        int l = bid >> 6, q = bid & 63; tr = q >> 4; tc = q & 15;
        src = cW1 + l * CC * CH; dst = cW1Tb + l * CH * CC; R = CC; Cs = CH; oC = CC;
    } else if (bid < 256) {     // cW2 [l][512][128] -> [l][128][512]
        int b = bid - 128, l = b >> 6, q = b & 63; tr = q & 15; tc = q >> 4;
        src = cW2 + l * CH * CC; dst = cW2Tb + l * CC * CH; R = CH; Cs = CC; oC = CH;
    } else {                    // proj_W [228][128] -> [128][256] (zero-pad rows>=228)
        int b = bid - 256; tr = b >> 2; tc = b & 3;
        src = proj_W; dst = projWTb; R = 228; Cs = CC; oC = 256;
    }
    const int tx = threadIdx.x & 31, ty0 = threadIdx.x >> 5;
    #pragma unroll
    for (int i = 0; i < 4; ++i) {
        int ty = ty0 + i * 8;
        int rr = tr * 32 + ty, cc = tc * 32 + tx;
        tile[ty][tx] = (rr < R) ? src[rr * Cs + cc] : 0.0f;
    }
    __syncthreads();
    #pragma unroll
    for (int i = 0; i < 4; ++i) {
        int ty = ty0 + i * 8;
        int orow = tc * 32 + ty, ocol = tr * 32 + tx;
        dst[orow * oC + ocol] = f2bf(tile[tx][ty]);
    }
}

// ---- fully fused: mixer + masked mean + tg gather + output GEMM ----------
__global__ __launch_bounds__(256, 4)
void gm_mixer(const float* __restrict__ edge_feat,
              const float* __restrict__ seed_times,
              const float* __restrict__ nbr_time,
              const float* __restrict__ time_w,
              const float* __restrict__ proj_b,
              const float* __restrict__ ln1_g, const float* __restrict__ ln1_b,
              const float* __restrict__ tb1,   const float* __restrict__ tb2,
              const float* __restrict__ ln2_g, const float* __restrict__ ln2_b,
              const float* __restrict__ cb1,   const float* __restrict__ cb2,
              const int*   __restrict__ nbr_nids,
              const unsigned short* __restrict__ projWTb,
              const unsigned short* __restrict__ tW1Tb,
              const unsigned short* __restrict__ tW2Tb,
              const unsigned short* __restrict__ cW1Tb,
              const unsigned short* __restrict__ cW2Tb,
              const float* __restrict__ node_feat,
              const float* __restrict__ out_W,
              const float* __restrict__ out_b,
              const int*   __restrict__ tg_idx,
              const int*   __restrict__ seed_ids,
              const int*   __restrict__ seg_lo,
              float* __restrict__ outp)
{
    __shared__ short ubuf[17408];                  // 34,816 B phase-union
    __shared__ float lnS[256], lnS2[256];          //  2,048 B LN partials
    __shared__ float mArr[KT], rArr[KT], maskArr[KT], dtArr[KT];

    const int n  = blockIdx.x;
    const int t  = threadIdx.x;
    const int w  = t >> 6;
    const int l  = t & 63;
    const int lr = l & 15;
    const int kg = l >> 4;
    const int c0 = w * 32 + lr;
    const int c1 = c0 + 16;

    short* Ab    = ubuf;               // [64][PSA]  projection A (half-K)
    short* LNz1T = ubuf;               // [128][PSK] LN1(z)^T
    short* G2T   = ubuf + 128 * PSK;   // [128][PSH] token hidden^T
    short* LNzb  = ubuf;               // [64][PS]   LN2(z)
    short* Gb    = ubuf + 64 * PS;     // [64][PS]   gelu chunk

    const f32x4 zero4 = {0.f, 0.f, 0.f, 0.f};
    f32x4 zr[4][2];                    // residual stream z, fp32, C-fragment layout

    if (t < KT) {
        dtArr[t]   = seed_times[n] - nbr_time[n * KT + t];
        maskArr[t] = (nbr_nids[n * KT + t] != 0) ? 1.0f : 0.0f;
    }
    // stage Ab pass1: edge_feat (K cols 0..127)
    {
        const float4* ef4 = (const float4*)(edge_feat + (size_t)n * KT * CC);
        #pragma unroll
        for (int it = 0; it < 8; ++it) {
            int i4 = it * 256 + t;
            int k = i4 >> 5, c = (i4 & 31) << 2;
            float4 v = ef4[i4];
            uint2 pk; pk.x = pk_bf16(v.x, v.y); pk.y = pk_bf16(v.z, v.w);
            *(uint2*)&Ab[k * PSA + c] = pk;
        }
    }
    __syncthreads();

    // ---------- projection: M=64, N=128, K=256 in two half-K passes
    {
        f32x4 acc[4][2];
        #pragma unroll
        for (int mt = 0; mt < 4; ++mt) { acc[mt][0] = zero4; acc[mt][1] = zero4; }
        #pragma unroll
        for (int p = 0; p < 2; ++p) {
            #pragma unroll
            for (int ks = 0; ks < 4; ++ks) {
                const unsigned short* bp = projWTb + (w * 32 + lr) * 256 + p * 128 + ks * 32 + kg * 8;
                bf16x8 b0 = *(const bf16x8*)bp;
                bf16x8 b1 = *(const bf16x8*)(bp + 16 * 256);
                #pragma unroll
                for (int mt = 0; mt < 4; ++mt) {
                    bf16x8 a = *(const bf16x8*)&Ab[(mt * 16 + lr) * PSA + ks * 32 + kg * 8];
                    acc[mt][0] = __builtin_amdgcn_mfma_f32_16x16x32_bf16(a, b0, acc[mt][0], 0, 0, 0);
                    acc[mt][1] = __builtin_amdgcn_mfma_f32_16x16x32_bf16(a, b1, acc[mt][1], 0, 0, 0);
                }
            }
            if (p == 0) {
                __syncthreads();        // all waves done reading Ab pass1
                // stage Ab pass2: time features
                #pragma unroll
                for (int it = 0; it < 16; ++it) {
                    int idx = it * 256 + t;
                    int k = idx >> 6, j2 = (idx & 63) << 1;
                    unsigned pk = 0;
                    if (j2 < TDIM) {
                        float dt = dtArr[k];
                        float2 twv = *(const float2*)&time_w[j2];
                        pk = pk_bf16(fast_cos2pi(dt * twv.x * 0.15915494309f),
                                     fast_cos2pi(dt * twv.y * 0.15915494309f));
                    }
                    *(unsigned*)&Ab[k * PSA + j2] = pk;
                }
                __syncthreads();
            }
        }
        #pragma unroll
        for (int mt = 0; mt < 4; ++mt)
            #pragma unroll
            for (int nt = 0; nt < 2; ++nt) {
                float pb = proj_b[nt ? c1 : c0];
                #pragma unroll
                for (int r = 0; r < 4; ++r) zr[mt][nt][r] = acc[mt][nt][r] + pb;
            }
    }

    for (int lay = 0; lay < 2; ++lay) {
        // ---------- LN1 stats: butterfly over lr + cross-wave LDS combine
        #pragma unroll
        for (int mt = 0; mt < 4; ++mt) {
            f32x4 sv, qv;
            #pragma unroll
            for (int r = 0; r < 4; ++r) {
                float z0 = zr[mt][0][r], z1 = zr[mt][1][r];
                sv[r] = z0 + z1;
                qv[r] = z0 * z0 + z1 * z1;
            }
            #pragma unroll
            for (int d = 1; d < 16; d <<= 1)
                #pragma unroll
                for (int r = 0; r < 4; ++r) {
                    sv[r] += __shfl_xor(sv[r], d);
                    qv[r] += __shfl_xor(qv[r], d);
                }
            if (lr == 0) {
                *(f32x4*)&lnS [w * 64 + mt * 16 + kg * 4] = sv;
                *(f32x4*)&lnS2[w * 64 + mt * 16 + kg * 4] = qv;
            }
        }
        __syncthreads();
        if (t < KT) {
            float s  = lnS [t] + lnS [64 + t] + lnS [128 + t] + lnS [192 + t];
            float s2 = lnS2[t] + lnS2[64 + t] + lnS2[128 + t] + lnS2[192 + t];
            float m = s * (1.0f / CC);
            float var = s2 * (1.0f / CC) - m * m;
            mArr[t] = m; rArr[t] = rsqrtf(var + 1e-5f);
        }
        __syncthreads();

        // ---------- LNz1T[c][k] from registers (wave-local c rows)
        {
            const float* g1 = ln1_g + lay * CC;
            const float* b1 = ln1_b + lay * CC;
            float gc0 = g1[c0], bc0 = b1[c0], gc1 = g1[c1], bc1 = b1[c1];
            #pragma unroll
            for (int mt = 0; mt < 4; ++mt) {
                f32x4 mv = *(const f32x4*)&mArr[mt * 16 + kg * 4];
                f32x4 rv = *(const f32x4*)&rArr[mt * 16 + kg * 4];
                #pragma unroll
                for (int nt = 0; nt < 2; ++nt) {
                    float gg = nt ? gc1 : gc0, bb = nt ? bc1 : bc0;
                    int c = nt ? c1 : c0;
                    float v0 = (zr[mt][nt][0] - mv[0]) * rv[0] * gg + bb;
                    float v1 = (zr[mt][nt][1] - mv[1]) * rv[1] * gg + bb;
                    float v2 = (zr[mt][nt][2] - mv[2]) * rv[2] * gg + bb;
                    float v3 = (zr[mt][nt][3] - mv[3]) * rv[3] * gg + bb;
                    uint2 pk; pk.x = pk_bf16(v0, v1); pk.y = pk_bf16(v2, v3);
                    *(uint2*)&LNz1T[c * PSK + mt * 16 + kg * 4] = pk;
                }
            }
        }
        // no barrier: token mix is fully wave-local in c

        // ---------- token mix 1: C[hh][c] -> gelu -> G2T[c][hh]
        {
            f32x4 acc1[2][2];
            #pragma unroll
            for (int mt = 0; mt < 2; ++mt) { acc1[mt][0] = zero4; acc1[mt][1] = zero4; }
            #pragma unroll
            for (int ks = 0; ks < 2; ++ks) {
                bf16x8 bb0 = *(const bf16x8*)&LNz1T[c0 * PSK + ks * 32 + kg * 8];
                bf16x8 bb1 = *(const bf16x8*)&LNz1T[c1 * PSK + ks * 32 + kg * 8];
                #pragma unroll
                for (int mt = 0; mt < 2; ++mt) {
                    bf16x8 a = *(const bf16x8*)&tW1Tb[lay * 2048 + (mt * 16 + lr) * 64 + ks * 32 + kg * 8];
                    acc1[mt][0] = __builtin_amdgcn_mfma_f32_16x16x32_bf16(a, bb0, acc1[mt][0], 0, 0, 0);
                    acc1[mt][1] = __builtin_amdgcn_mfma_f32_16x16x32_bf16(a, bb1, acc1[mt][1], 0, 0, 0);
                }
            }
            #pragma unroll
            for (int mt = 0; mt < 2; ++mt) {
                float4 tbv = *(const float4*)&tb1[lay * TH + mt * 16 + kg * 4];
                #pragma unroll
                for (int nt = 0; nt < 2; ++nt) {
                    int c = nt ? c1 : c0;
                    float g0 = gelu_f(acc1[mt][nt][0] + tbv.x);
                    float g1v = gelu_f(acc1[mt][nt][1] + tbv.y);
                    float g2 = gelu_f(acc1[mt][nt][2] + tbv.z);
                    float g3 = gelu_f(acc1[mt][nt][3] + tbv.w);
                    uint2 pk; pk.x = pk_bf16(g0, g1v); pk.y = pk_bf16(g2, g3);
                    *(uint2*)&G2T[c * PSH + mt * 16 + kg * 4] = pk;
                }
            }
        }
        // ---------- token mix 2: z += C (registers)
        {
            bf16x8 bb0 = *(const bf16x8*)&G2T[c0 * PSH + kg * 8];
            bf16x8 bb1 = *(const bf16x8*)&G2T[c1 * PSH + kg * 8];
            #pragma unroll
            for (int mt = 0; mt < 4; ++mt) {
                f32x4 a2v0 = zero4, a2v1 = zero4;
                bf16x8 a = *(const bf16x8*)&tW2Tb[lay * 2048 + (mt * 16 + lr) * 32 + kg * 8];
                a2v0 = __builtin_amdgcn_mfma_f32_16x16x32_bf16(a, bb0, a2v0, 0, 0, 0);
                a2v1 = __builtin_amdgcn_mfma_f32_16x16x32_bf16(a, bb1, a2v1, 0, 0, 0);
                float4 t2v = *(const float4*)&tb2[lay * KT + mt * 16 + kg * 4];
                #pragma unroll
                for (int r = 0; r < 4; ++r) {
                    float tb = (r == 0) ? t2v.x : (r == 1) ? t2v.y : (r == 2) ? t2v.z : t2v.w;
                    zr[mt][0][r] += a2v0[r] + tb;
                    zr[mt][1][r] += a2v1[r] + tb;
                }
            }
        }

        // ---------- LN2 stats (same scheme)
        #pragma unroll
        for (int mt = 0; mt < 4; ++mt) {
            f32x4 sv, qv;
            #pragma unroll
            for (int r = 0; r < 4; ++r) {
                float z0 = zr[mt][0][r], z1 = zr[mt][1][r];
                sv[r] = z0 + z1;
                qv[r] = z0 * z0 + z1 * z1;
            }
            #pragma unroll
            for (int d = 1; d < 16; d <<= 1)
                #pragma unroll
                for (int r = 0; r < 4; ++r) {
                    sv[r] += __shfl_xor(sv[r], d);
                    qv[r] += __shfl_xor(qv[r], d);
                }
            if (lr == 0) {
                *(f32x4*)&lnS [w * 64 + mt * 16 + kg * 4] = sv;
                *(f32x4*)&lnS2[w * 64 + mt * 16 + kg * 4] = qv;
            }
        }
        __syncthreads();
        if (t < KT) {
            float s  = lnS [t] + lnS [64 + t] + lnS [128 + t] + lnS [192 + t];
            float s2 = lnS2[t] + lnS2[64 + t] + lnS2[128 + t] + lnS2[192 + t];
            float m = s * (1.0f / CC);
            float var = s2 * (1.0f / CC) - m * m;
            mArr[t] = m; rArr[t] = rsqrtf(var + 1e-5f);
        }
        __syncthreads();

        // ---------- LNzb[k][c] from registers (lane-pair packed b32 writes)
        {
            const float* g2 = ln2_g + lay * CC;
            const float* b2 = ln2_b + lay * CC;
            float gc0 = g2[c0], bc0 = b2[c0], gc1 = g2[c1], bc1 = b2[c1];
            const bool odd = lr & 1;
            const int cb = odd ? (c1 - 1) : c0;
            #pragma unroll
            for (int mt = 0; mt < 4; ++mt) {
                f32x4 mv = *(const f32x4*)&mArr[mt * 16 + kg * 4];
                f32x4 rv = *(const f32x4*)&rArr[mt * 16 + kg * 4];
                #pragma unroll
                for (int r = 0; r < 4; ++r) {
                    float v0 = (zr[mt][0][r] - mv[r]) * rv[r] * gc0 + bc0;
                    float v1 = (zr[mt][1][r] - mv[r]) * rv[r] * gc1 + bc1;
                    float s0 = __shfl_xor(v0, 1);
                    float s1 = __shfl_xor(v1, 1);
                    unsigned pka = pk_bf16(v0, s0);
                    unsigned pkb = pk_bf16(s1, v1);
                    unsigned pkv = odd ? pkb : pka;
                    *(unsigned*)&LNzb[(mt * 16 + kg * 4 + r) * PS + cb] = pkv;
                }
            }
        }
        __syncthreads();   // LNzb is read cross-wave

        // ---------- channel mix: 4 hidden chunks of 128
        {
            f32x4 accB[4][2];
            #pragma unroll
            for (int mt = 0; mt < 4; ++mt) { accB[mt][0] = zero4; accB[mt][1] = zero4; }

            for (int jc = 0; jc < 4; ++jc) {
                f32x4 accA[4][2];
                #pragma unroll
                for (int mt = 0; mt < 4; ++mt) { accA[mt][0] = zero4; accA[mt][1] = zero4; }
                __builtin_amdgcn_s_setprio(1);
                #pragma unroll
                for (int ks = 0; ks < 4; ++ks) {
                    const unsigned short* w1p = cW1Tb + lay * CH * CC
                                              + (jc * 128 + w * 32 + lr) * CC + ks * 32 + kg * 8;
                    bf16x8 a0 = *(const bf16x8*)w1p;
                    bf16x8 a1 = *(const bf16x8*)(w1p + 16 * CC);
                    #pragma unroll
                    for (int mt = 0; mt < 4; ++mt) {
                        bf16x8 b = *(const bf16x8*)&LNzb[(mt * 16 + lr) * PS + ks * 32 + kg * 8];
                        accA[mt][0] = __builtin_amdgcn_mfma_f32_16x16x32_bf16(a0, b, accA[mt][0], 0, 0, 0);
                        accA[mt][1] = __builtin_amdgcn_mfma_f32_16x16x32_bf16(a1, b, accA[mt][1], 0, 0, 0);
                    }
                }
                __builtin_amdgcn_s_setprio(0);
                #pragma unroll
                for (int nt = 0; nt < 2; ++nt) {
                    int j0 = w * 32 + nt * 16 + kg * 4;
                    float4 cbv = *(const float4*)&cb1[lay * CH + jc * 128 + j0];
                    #pragma unroll
                    for (int mt = 0; mt < 4; ++mt) {
                        float g0 = gelu_f(accA[mt][nt][0] + cbv.x);
                        float g1v = gelu_f(accA[mt][nt][1] + cbv.y);
                        float g2 = gelu_f(accA[mt][nt][2] + cbv.z);
                        float g3 = gelu_f(accA[mt][nt][3] + cbv.w);
                        uint2 pk; pk.x = pk_bf16(g0, g1v); pk.y = pk_bf16(g2, g3);
                        *(uint2*)&Gb[(mt * 16 + lr) * PS + j0] = pk;
                    }
                }
                __syncthreads();
                __builtin_amdgcn_s_setprio(1);
                #pragma unroll
                for (int ks = 0; ks < 4; ++ks) {
                    const unsigned short* w2p = cW2Tb + lay * CC * CH
                                              + (w * 32 + lr) * CH + jc * 128 + ks * 32 + kg * 8;
                    bf16x8 b0 = *(const bf16x8*)w2p;
                    bf16x8 b1 = *(const bf16x8*)(w2p + 16 * CH);
                    #pragma unroll
                    for (int mt = 0; mt < 4; ++mt) {
                        bf16x8 a = *(const bf16x8*)&Gb[(mt * 16 + lr) * PS + ks * 32 + kg * 8];
                        accB[mt][0] = __builtin_amdgcn_mfma_f32_16x16x32_bf16(a, b0, accB[mt][0], 0, 0, 0);
                        accB[mt][1] = __builtin_amdgcn_mfma_f32_16x16x32_bf16(a, b1, accB[mt][1], 0, 0, 0);
                    }
                }
                __builtin_amdgcn_s_setprio(0);
                __syncthreads();
            }
            #pragma unroll
            for (int mt = 0; mt < 4; ++mt)
                #pragma unroll
                for (int nt = 0; nt < 2; ++nt) {
                    float cb = cb2[lay * CC + (nt ? c1 : c0)];
                    #pragma unroll
                    for (int r = 0; r < 4; ++r) zr[mt][nt][r] += accB[mt][nt][r] + cb;
                }
        }
    }

    // ---------- fused epilogue: masked mean + tg gather + output GEMM ------
    float* redf = (float*)ubuf;        // [8][132]
    float* zmL  = redf + 8 * 132;      // [128]
    float* znL  = zmL + 128;           // [128]
    float* oL   = znL + 128;           // [256]

    // masked mean over K from registers -> zmL
    {
        float msum = 0.f, a0v = 0.f, a1v = 0.f;
        #pragma unroll
        for (int mt = 0; mt < 4; ++mt) {
            f32x4 mk4 = *(const f32x4*)&maskArr[mt * 16 + kg * 4];
            #pragma unroll
            for (int r = 0; r < 4; ++r) {
                msum += mk4[r];
                a0v  += zr[mt][0][r] * mk4[r];
                a1v  += zr[mt][1][r] * mk4[r];
            }
        }
        a0v  += __shfl_xor(a0v, 16);  a0v  += __shfl_xor(a0v, 32);
        a1v  += __shfl_xor(a1v, 16);  a1v  += __shfl_xor(a1v, 32);
        msum += __shfl_xor(msum, 16); msum += __shfl_xor(msum, 32);
        if (kg == 0) {
            float inv = fast_rcp(fmaxf(msum, 1.0f));
            zmL[c0] = a0v * inv;
            zmL[c1] = a1v * inv;
        }
    }

    // tg ragged gather (8 rows in flight, float4 per 32-lane group)
    const int lo = seg_lo[n], hi = seg_lo[n + 1];
    {
        const int q = t & 31, g = t >> 5;
        float4 acc = {0.f, 0.f, 0.f, 0.f};
        for (int i = lo + g; i < hi; i += 8) {
            const float4* nf = (const float4*)(node_feat + (size_t)tg_idx[i] * CC);
            float4 v = nf[q];
            acc.x += v.x; acc.y += v.y; acc.z += v.z; acc.w += v.w;
        }
        *(float4*)&redf[g * 132 + q * 4] = acc;
    }
    __syncthreads();
    if (t < CC) {
        float s = 0.f;
        #pragma unroll
        for (int gg = 0; gg < 8; ++gg) s += redf[gg * 132 + t];
        float cnt = (float)(hi - lo);
        znL[t] = s / fmaxf(cnt, 1.0f) + node_feat[(size_t)seed_ids[n] * CC + t];
    }
    __syncthreads();
    // output GEMM: [zm|zn] (1x256) @ out_W (256x128)
    {
        const int c = t & 127, h = t >> 7;
        const float* src = h ? znL : zmL;
        const float* Wp  = out_W + (size_t)h * CC * 128;
        float o = 0.f;
        for (int j = 0; j < CC; ++j) o += src[j] * Wp[j * 128 + c];
        oL[h * 128 + c] = o;
    }
    __syncthreads();
    if (t < CC) outp[n * 128 + t] = oL[t] + oL[CC + t] + out_b[t];
}

extern "C" void kernel_launch(void* const* d_in, const int* in_sizes, int n_in,
                              void* d_out, int out_size, void* d_ws, size_t ws_size,
                              hipStream_t stream)
{
    const float* edge_feat  = (const float*)d_in[0];
    const float* seed_times = (const float*)d_in[1];
    const float* nbr_time   = (const float*)d_in[2];
    const float* node_feat  = (const float*)d_in[3];
    const float* time_w     = (const float*)d_in[4];
    const float* proj_W     = (const float*)d_in[5];
    const float* proj_b     = (const float*)d_in[6];
    const float* ln1_g      = (const float*)d_in[7];
    const float* ln1_b      = (const float*)d_in[8];
    const float* tW1        = (const float*)d_in[9];
    const float* tb1        = (const float*)d_in[10];
    const float* tW2        = (const float*)d_in[11];
    const float* tb2        = (const float*)d_in[12];
    const float* ln2_g      = (const float*)d_in[13];
    const float* ln2_b      = (const float*)d_in[14];
    const float* cW1        = (const float*)d_in[15];
    const float* cb1        = (const float*)d_in[16];
    const float* cW2        = (const float*)d_in[17];
    const float* cb2        = (const float*)d_in[18];
    const float* out_W      = (const float*)d_in[19];
    const float* out_b      = (const float*)d_in[20];
    const int*   nbr_nids   = (const int*)d_in[21];
    const int*   tg_idx     = (const int*)d_in[22];
    const int*   tg_seg     = (const int*)d_in[23];
    const int*   seed_ids   = (const int*)d_in[24];

    char* ws = (char*)d_ws;
    int*            seg_lo  = (int*)ws;                              //    12,292 B
    unsigned short* projWTb = (unsigned short*)(ws + 16384);         //    65,536 B
    unsigned short* tW1Tb   = (unsigned short*)(ws + 81920);         //     8,192 B
    unsigned short* tW2Tb   = (unsigned short*)(ws + 90112);         //     8,192 B
    unsigned short* cW1Tb   = (unsigned short*)(ws + 98304);         //   262,144 B
    unsigned short* cW2Tb   = (unsigned short*)(ws + 360448);        //   262,144 B

    gm_prep<<<333, 256, 0, stream>>>(cW1, cW2, proj_W, tW1, tW2, tg_seg,
                                     cW1Tb, cW2Tb, projWTb, tW1Tb, tW2Tb, seg_lo);
    gm_mixer<<<NS, 256, 0, stream>>>(edge_feat, seed_times, nbr_time, time_w,
                                     proj_b, ln1_g, ln1_b, tb1, tb2, ln2_g, ln2_b,
                                     cb1, cb2, nbr_nids,
                                     projWTb, tW1Tb, tW2Tb, cW1Tb, cW2Tb,
                                     node_feat, out_W, out_b, tg_idx, seed_ids, seg_lo,
                                     (float*)d_out);
}

// Round 6
// 536.304 us; speedup vs baseline: 1.0617x; 1.0617x over previous
//
#include <hip/hip_runtime.h>
#include <math.h>

#define NS   3072
#define KT   64
#define CC   128
#define TDIM 100
#define TGN  98304
#define TH   32
#define CH   512
#define PS   136   // LNzb/Gb bf16 stride (272 B rows, 16B-aligned)
#define PSA  136   // Ab half-K stride
#define PSK  72    // LNz1T stride (144 B)
#define PSH  40    // G2T stride (80 B)

typedef __attribute__((ext_vector_type(8))) short bf16x8;
typedef __attribute__((ext_vector_type(4))) float f32x4;

__device__ __forceinline__ unsigned short f2bf(float f) {
    unsigned int u = __float_as_uint(f);
    return (unsigned short)((u + 0x7FFFu + ((u >> 16) & 1u)) >> 16);   // RNE
}
__device__ __forceinline__ float fast_exp2(float x) {
    float r; asm("v_exp_f32 %0, %1" : "=v"(r) : "v"(x)); return r;
}
__device__ __forceinline__ float fast_rcp(float x) {
    float r; asm("v_rcp_f32 %0, %1" : "=v"(r) : "v"(x)); return r;
}
__device__ __forceinline__ float fast_cos2pi(float rev) {   // cos(2*pi*rev)
    float f = rev - floorf(rev);
    float r; asm("v_cos_f32 %0, %1" : "=v"(r) : "v"(f)); return r;
}
__device__ __forceinline__ unsigned int pk_bf16(float lo, float hi) {
    unsigned int r; asm("v_cvt_pk_bf16_f32 %0, %1, %2" : "=v"(r) : "v"(lo), "v"(hi)); return r;
}
__device__ __forceinline__ float gelu_f(float x) {
    float p = x * x;
    float e = fast_exp2(-x * fmaf(p, 0.1029436f, 2.3022082f));
    return x * fast_rcp(1.0f + e);
}

// ---- single prep kernel: tiled weight transposes + small transposes + seg bounds
__global__ __launch_bounds__(256)
void gm_prep(const float* __restrict__ cW1, const float* __restrict__ cW2,
             const float* __restrict__ proj_W,
             const float* __restrict__ tW1, const float* __restrict__ tW2,
             const int*   __restrict__ tg_seg,
             unsigned short* __restrict__ cW1Tb, unsigned short* __restrict__ cW2Tb,
             unsigned short* __restrict__ projWTb,
             unsigned short* __restrict__ tW1Tb, unsigned short* __restrict__ tW2Tb,
             int* __restrict__ seg_lo)
{
    __shared__ float tile[32][33];
    const int bid = blockIdx.x;
    if (bid >= 288) {   // small path: tW1T, tW2T, seg_lo
        int e = (bid - 288) * 256 + threadIdx.x;   // 0..11519
        if (e < 4096) {           // tW1T[l][h][k]
            int l = e >> 11, rem = e & 2047, h = rem >> 6, k = rem & 63;
            tW1Tb[e] = f2bf(tW1[(l * KT + k) * TH + h]);
        } else if (e < 8192) {    // tW2T[l][k][h]
            int e2 = e - 4096, l = e2 >> 11, rem = e2 & 2047, k = rem >> 5, h = rem & 31;
            tW2Tb[e2] = f2bf(tW2[(l * TH + h) * KT + k]);
        } else if (e < 8192 + 3073) {  // seg_lo[n] = lower_bound(tg_seg, n)
            int nn = e - 8192;
            int a = 0, b = TGN;
            while (a < b) { int mm = (a + b) >> 1; if (tg_seg[mm] < nn) a = mm + 1; else b = mm; }
            seg_lo[nn] = a;
        }
        return;
    }
    const float* src; unsigned short* dst;
    int R, Cs, oC, tr, tc;
    if (bid < 128) {            // cW1 [l][128][512] -> [l][512][128]
        int l = bid >> 6, q = bid & 63; tr = q >> 4; tc = q & 15;
        src = cW1 + l * CC * CH; dst = cW1Tb + l * CH * CC; R = CC; Cs = CH; oC = CC;
    } else if (bid < 256) {     // cW2 [l][512][128] -> [l][128][512]
        int b = bid - 128, l = b >> 6, q = b & 63; tr = q & 15; tc = q >> 4;
        src = cW2 + l * CH * CC; dst = cW2Tb + l * CC * CH; R = CH; Cs = CC; oC = CH;
    } else {                    // proj_W [228][128] -> [128][256] (zero-pad rows>=228)
        int b = bid - 256; tr = b >> 2; tc = b & 3;
        src = proj_W; dst = projWTb; R = 228; Cs = CC; oC = 256;
    }
    const int tx = threadIdx.x & 31, ty0 = threadIdx.x >> 5;
    #pragma unroll
    for (int i = 0; i < 4; ++i) {
        int ty = ty0 + i * 8;
        int rr = tr * 32 + ty, cc = tc * 32 + tx;
        tile[ty][tx] = (rr < R) ? src[rr * Cs + cc] : 0.0f;
    }
    __syncthreads();
    #pragma unroll
    for (int i = 0; i < 4; ++i) {
        int ty = ty0 + i * 8;
        int orow = tc * 32 + ty, ocol = tr * 32 + tx;
        dst[orow * oC + ocol] = f2bf(tile[tx][ty]);
    }
}

// ---- fully fused: mixer + masked mean + tg gather + output GEMM ----------
// launch_bounds(256,3): R4-proven no-spill point (VGPR=84). (256,4) forced
// VGPR=64 and spilled ~180 MB of accumulators to scratch (R5: WRITE_SIZE 232MB).
__global__ __launch_bounds__(256, 3)
void gm_mixer(const float* __restrict__ edge_feat,
              const float* __restrict__ seed_times,
              const float* __restrict__ nbr_time,
              const float* __restrict__ time_w,
              const float* __restrict__ proj_b,
              const float* __restrict__ ln1_g, const float* __restrict__ ln1_b,
              const float* __restrict__ tb1,   const float* __restrict__ tb2,
              const float* __restrict__ ln2_g, const float* __restrict__ ln2_b,
              const float* __restrict__ cb1,   const float* __restrict__ cb2,
              const int*   __restrict__ nbr_nids,
              const unsigned short* __restrict__ projWTb,
              const unsigned short* __restrict__ tW1Tb,
              const unsigned short* __restrict__ tW2Tb,
              const unsigned short* __restrict__ cW1Tb,
              const unsigned short* __restrict__ cW2Tb,
              const float* __restrict__ node_feat,
              const float* __restrict__ out_W,
              const float* __restrict__ out_b,
              const int*   __restrict__ tg_idx,
              const int*   __restrict__ seed_ids,
              const int*   __restrict__ seg_lo,
              float* __restrict__ outp)
{
    __shared__ short ubuf[17408];                  // 34,816 B phase-union
    __shared__ float lnS[256], lnS2[256];          //  2,048 B LN partials
    __shared__ float mArr[KT], rArr[KT], maskArr[KT], dtArr[KT];

    const int n  = blockIdx.x;
    const int t  = threadIdx.x;
    const int w  = t >> 6;
    const int l  = t & 63;
    const int lr = l & 15;
    const int kg = l >> 4;
    const int c0 = w * 32 + lr;
    const int c1 = c0 + 16;

    short* Ab    = ubuf;               // [64][PSA]  projection A (half-K)
    short* LNz1T = ubuf;               // [128][PSK] LN1(z)^T
    short* G2T   = ubuf + 128 * PSK;   // [128][PSH] token hidden^T
    short* LNzb  = ubuf;               // [64][PS]   LN2(z)
    short* Gb    = ubuf + 64 * PS;     // [64][PS]   gelu chunk

    const f32x4 zero4 = {0.f, 0.f, 0.f, 0.f};
    f32x4 zr[4][2];                    // residual stream z, fp32, C-fragment layout

    if (t < KT) {
        dtArr[t]   = seed_times[n] - nbr_time[n * KT + t];
        maskArr[t] = (nbr_nids[n * KT + t] != 0) ? 1.0f : 0.0f;
    }
    // stage Ab pass1: edge_feat (K cols 0..127)
    {
        const float4* ef4 = (const float4*)(edge_feat + (size_t)n * KT * CC);
        #pragma unroll
        for (int it = 0; it < 8; ++it) {
            int i4 = it * 256 + t;
            int k = i4 >> 5, c = (i4 & 31) << 2;
            float4 v = ef4[i4];
            uint2 pk; pk.x = pk_bf16(v.x, v.y); pk.y = pk_bf16(v.z, v.w);
            *(uint2*)&Ab[k * PSA + c] = pk;
        }
    }
    __syncthreads();

    // ---------- projection: M=64, N=128, K=256 in two half-K passes
    {
        f32x4 acc[4][2];
        #pragma unroll
        for (int mt = 0; mt < 4; ++mt) { acc[mt][0] = zero4; acc[mt][1] = zero4; }
        #pragma unroll
        for (int p = 0; p < 2; ++p) {
            #pragma unroll
            for (int ks = 0; ks < 4; ++ks) {
                const unsigned short* bp = projWTb + (w * 32 + lr) * 256 + p * 128 + ks * 32 + kg * 8;
                bf16x8 b0 = *(const bf16x8*)bp;
                bf16x8 b1 = *(const bf16x8*)(bp + 16 * 256);
                #pragma unroll
                for (int mt = 0; mt < 4; ++mt) {
                    bf16x8 a = *(const bf16x8*)&Ab[(mt * 16 + lr) * PSA + ks * 32 + kg * 8];
                    acc[mt][0] = __builtin_amdgcn_mfma_f32_16x16x32_bf16(a, b0, acc[mt][0], 0, 0, 0);
                    acc[mt][1] = __builtin_amdgcn_mfma_f32_16x16x32_bf16(a, b1, acc[mt][1], 0, 0, 0);
                }
            }
            if (p == 0) {
                __syncthreads();        // all waves done reading Ab pass1
                // stage Ab pass2: time features
                #pragma unroll
                for (int it = 0; it < 16; ++it) {
                    int idx = it * 256 + t;
                    int k = idx >> 6, j2 = (idx & 63) << 1;
                    unsigned pk = 0;
                    if (j2 < TDIM) {
                        float dt = dtArr[k];
                        float2 twv = *(const float2*)&time_w[j2];
                        pk = pk_bf16(fast_cos2pi(dt * twv.x * 0.15915494309f),
                                     fast_cos2pi(dt * twv.y * 0.15915494309f));
                    }
                    *(unsigned*)&Ab[k * PSA + j2] = pk;
                }
                __syncthreads();
            }
        }
        #pragma unroll
        for (int mt = 0; mt < 4; ++mt)
            #pragma unroll
            for (int nt = 0; nt < 2; ++nt) {
                float pb = proj_b[nt ? c1 : c0];
                #pragma unroll
                for (int r = 0; r < 4; ++r) zr[mt][nt][r] = acc[mt][nt][r] + pb;
            }
    }

    for (int lay = 0; lay < 2; ++lay) {
        // ---------- LN1 stats: butterfly over lr + cross-wave LDS combine
        #pragma unroll
        for (int mt = 0; mt < 4; ++mt) {
            f32x4 sv, qv;
            #pragma unroll
            for (int r = 0; r < 4; ++r) {
                float z0 = zr[mt][0][r], z1 = zr[mt][1][r];
                sv[r] = z0 + z1;
                qv[r] = z0 * z0 + z1 * z1;
            }
            #pragma unroll
            for (int d = 1; d < 16; d <<= 1)
                #pragma unroll
                for (int r = 0; r < 4; ++r) {
                    sv[r] += __shfl_xor(sv[r], d);
                    qv[r] += __shfl_xor(qv[r], d);
                }
            if (lr == 0) {
                *(f32x4*)&lnS [w * 64 + mt * 16 + kg * 4] = sv;
                *(f32x4*)&lnS2[w * 64 + mt * 16 + kg * 4] = qv;
            }
        }
        __syncthreads();
        if (t < KT) {
            float s  = lnS [t] + lnS [64 + t] + lnS [128 + t] + lnS [192 + t];
            float s2 = lnS2[t] + lnS2[64 + t] + lnS2[128 + t] + lnS2[192 + t];
            float m = s * (1.0f / CC);
            float var = s2 * (1.0f / CC) - m * m;
            mArr[t] = m; rArr[t] = rsqrtf(var + 1e-5f);
        }
        __syncthreads();

        // ---------- LNz1T[c][k] from registers (wave-local c rows)
        {
            const float* g1 = ln1_g + lay * CC;
            const float* b1 = ln1_b + lay * CC;
            float gc0 = g1[c0], bc0 = b1[c0], gc1 = g1[c1], bc1 = b1[c1];
            #pragma unroll
            for (int mt = 0; mt < 4; ++mt) {
                f32x4 mv = *(const f32x4*)&mArr[mt * 16 + kg * 4];
                f32x4 rv = *(const f32x4*)&rArr[mt * 16 + kg * 4];
                #pragma unroll
                for (int nt = 0; nt < 2; ++nt) {
                    float gg = nt ? gc1 : gc0, bb = nt ? bc1 : bc0;
                    int c = nt ? c1 : c0;
                    float v0 = (zr[mt][nt][0] - mv[0]) * rv[0] * gg + bb;
                    float v1 = (zr[mt][nt][1] - mv[1]) * rv[1] * gg + bb;
                    float v2 = (zr[mt][nt][2] - mv[2]) * rv[2] * gg + bb;
                    float v3 = (zr[mt][nt][3] - mv[3]) * rv[3] * gg + bb;
                    uint2 pk; pk.x = pk_bf16(v0, v1); pk.y = pk_bf16(v2, v3);
                    *(uint2*)&LNz1T[c * PSK + mt * 16 + kg * 4] = pk;
                }
            }
        }
        // no barrier: token mix is fully wave-local in c

        // ---------- token mix 1: C[hh][c] -> gelu -> G2T[c][hh]
        {
            f32x4 acc1[2][2];
            #pragma unroll
            for (int mt = 0; mt < 2; ++mt) { acc1[mt][0] = zero4; acc1[mt][1] = zero4; }
            #pragma unroll
            for (int ks = 0; ks < 2; ++ks) {
                bf16x8 bb0 = *(const bf16x8*)&LNz1T[c0 * PSK + ks * 32 + kg * 8];
                bf16x8 bb1 = *(const bf16x8*)&LNz1T[c1 * PSK + ks * 32 + kg * 8];
                #pragma unroll
                for (int mt = 0; mt < 2; ++mt) {
                    bf16x8 a = *(const bf16x8*)&tW1Tb[lay * 2048 + (mt * 16 + lr) * 64 + ks * 32 + kg * 8];
                    acc1[mt][0] = __builtin_amdgcn_mfma_f32_16x16x32_bf16(a, bb0, acc1[mt][0], 0, 0, 0);
                    acc1[mt][1] = __builtin_amdgcn_mfma_f32_16x16x32_bf16(a, bb1, acc1[mt][1], 0, 0, 0);
                }
            }
            #pragma unroll
            for (int mt = 0; mt < 2; ++mt) {
                float4 tbv = *(const float4*)&tb1[lay * TH + mt * 16 + kg * 4];
                #pragma unroll
                for (int nt = 0; nt < 2; ++nt) {
                    int c = nt ? c1 : c0;
                    float g0 = gelu_f(acc1[mt][nt][0] + tbv.x);
                    float g1v = gelu_f(acc1[mt][nt][1] + tbv.y);
                    float g2 = gelu_f(acc1[mt][nt][2] + tbv.z);
                    float g3 = gelu_f(acc1[mt][nt][3] + tbv.w);
                    uint2 pk; pk.x = pk_bf16(g0, g1v); pk.y = pk_bf16(g2, g3);
                    *(uint2*)&G2T[c * PSH + mt * 16 + kg * 4] = pk;
                }
            }
        }
        // ---------- token mix 2: z += C (registers)
        {
            bf16x8 bb0 = *(const bf16x8*)&G2T[c0 * PSH + kg * 8];
            bf16x8 bb1 = *(const bf16x8*)&G2T[c1 * PSH + kg * 8];
            #pragma unroll
            for (int mt = 0; mt < 4; ++mt) {
                f32x4 a2v0 = zero4, a2v1 = zero4;
                bf16x8 a = *(const bf16x8*)&tW2Tb[lay * 2048 + (mt * 16 + lr) * 32 + kg * 8];
                a2v0 = __builtin_amdgcn_mfma_f32_16x16x32_bf16(a, bb0, a2v0, 0, 0, 0);
                a2v1 = __builtin_amdgcn_mfma_f32_16x16x32_bf16(a, bb1, a2v1, 0, 0, 0);
                float4 t2v = *(const float4*)&tb2[lay * KT + mt * 16 + kg * 4];
                #pragma unroll
                for (int r = 0; r < 4; ++r) {
                    float tb = (r == 0) ? t2v.x : (r == 1) ? t2v.y : (r == 2) ? t2v.z : t2v.w;
                    zr[mt][0][r] += a2v0[r] + tb;
                    zr[mt][1][r] += a2v1[r] + tb;
                }
            }
        }

        // ---------- LN2 stats (same scheme)
        #pragma unroll
        for (int mt = 0; mt < 4; ++mt) {
            f32x4 sv, qv;
            #pragma unroll
            for (int r = 0; r < 4; ++r) {
                float z0 = zr[mt][0][r], z1 = zr[mt][1][r];
                sv[r] = z0 + z1;
                qv[r] = z0 * z0 + z1 * z1;
            }
            #pragma unroll
            for (int d = 1; d < 16; d <<= 1)
                #pragma unroll
                for (int r = 0; r < 4; ++r) {
                    sv[r] += __shfl_xor(sv[r], d);
                    qv[r] += __shfl_xor(qv[r], d);
                }
            if (lr == 0) {
                *(f32x4*)&lnS [w * 64 + mt * 16 + kg * 4] = sv;
                *(f32x4*)&lnS2[w * 64 + mt * 16 + kg * 4] = qv;
            }
        }
        __syncthreads();
        if (t < KT) {
            float s  = lnS [t] + lnS [64 + t] + lnS [128 + t] + lnS [192 + t];
            float s2 = lnS2[t] + lnS2[64 + t] + lnS2[128 + t] + lnS2[192 + t];
            float m = s * (1.0f / CC);
            float var = s2 * (1.0f / CC) - m * m;
            mArr[t] = m; rArr[t] = rsqrtf(var + 1e-5f);
        }
        __syncthreads();

        // ---------- LNzb[k][c] from registers (lane-pair packed b32 writes)
        {
            const float* g2 = ln2_g + lay * CC;
            const float* b2 = ln2_b + lay * CC;
            float gc0 = g2[c0], bc0 = b2[c0], gc1 = g2[c1], bc1 = b2[c1];
            const bool odd = lr & 1;
            const int cb = odd ? (c1 - 1) : c0;
            #pragma unroll
            for (int mt = 0; mt < 4; ++mt) {
                f32x4 mv = *(const f32x4*)&mArr[mt * 16 + kg * 4];
                f32x4 rv = *(const f32x4*)&rArr[mt * 16 + kg * 4];
                #pragma unroll
                for (int r = 0; r < 4; ++r) {
                    float v0 = (zr[mt][0][r] - mv[r]) * rv[r] * gc0 + bc0;
                    float v1 = (zr[mt][1][r] - mv[r]) * rv[r] * gc1 + bc1;
                    float s0 = __shfl_xor(v0, 1);
                    float s1 = __shfl_xor(v1, 1);
                    unsigned pka = pk_bf16(v0, s0);
                    unsigned pkb = pk_bf16(s1, v1);
                    unsigned pkv = odd ? pkb : pka;
                    *(unsigned*)&LNzb[(mt * 16 + kg * 4 + r) * PS + cb] = pkv;
                }
            }
        }
        __syncthreads();   // LNzb is read cross-wave

        // ---------- channel mix: 4 hidden chunks of 128
        {
            f32x4 accB[4][2];
            #pragma unroll
            for (int mt = 0; mt < 4; ++mt) { accB[mt][0] = zero4; accB[mt][1] = zero4; }

            for (int jc = 0; jc < 4; ++jc) {
                f32x4 accA[4][2];
                #pragma unroll
                for (int mt = 0; mt < 4; ++mt) { accA[mt][0] = zero4; accA[mt][1] = zero4; }
                __builtin_amdgcn_s_setprio(1);
                #pragma unroll
                for (int ks = 0; ks < 4; ++ks) {
                    const unsigned short* w1p = cW1Tb + lay * CH * CC
                                              + (jc * 128 + w * 32 + lr) * CC + ks * 32 + kg * 8;
                    bf16x8 a0 = *(const bf16x8*)w1p;
                    bf16x8 a1 = *(const bf16x8*)(w1p + 16 * CC);
                    #pragma unroll
                    for (int mt = 0; mt < 4; ++mt) {
                        bf16x8 b = *(const bf16x8*)&LNzb[(mt * 16 + lr) * PS + ks * 32 + kg * 8];
                        accA[mt][0] = __builtin_amdgcn_mfma_f32_16x16x32_bf16(a0, b, accA[mt][0], 0, 0, 0);
                        accA[mt][1] = __builtin_amdgcn_mfma_f32_16x16x32_bf16(a1, b, accA[mt][1], 0, 0, 0);
                    }
                }
                __builtin_amdgcn_s_setprio(0);
                #pragma unroll
                for (int nt = 0; nt < 2; ++nt) {
                    int j0 = w * 32 + nt * 16 + kg * 4;
                    float4 cbv = *(const float4*)&cb1[lay * CH + jc * 128 + j0];
                    #pragma unroll
                    for (int mt = 0; mt < 4; ++mt) {
                        float g0 = gelu_f(accA[mt][nt][0] + cbv.x);
                        float g1v = gelu_f(accA[mt][nt][1] + cbv.y);
                        float g2 = gelu_f(accA[mt][nt][2] + cbv.z);
                        float g3 = gelu_f(accA[mt][nt][3] + cbv.w);
                        uint2 pk; pk.x = pk_bf16(g0, g1v); pk.y = pk_bf16(g2, g3);
                        *(uint2*)&Gb[(mt * 16 + lr) * PS + j0] = pk;
                    }
                }
                __syncthreads();
                __builtin_amdgcn_s_setprio(1);
                #pragma unroll
                for (int ks = 0; ks < 4; ++ks) {
                    const unsigned short* w2p = cW2Tb + lay * CC * CH
                                              + (w * 32 + lr) * CH + jc * 128 + ks * 32 + kg * 8;
                    bf16x8 b0 = *(const bf16x8*)w2p;
                    bf16x8 b1 = *(const bf16x8*)(w2p + 16 * CH);
                    #pragma unroll
                    for (int mt = 0; mt < 4; ++mt) {
                        bf16x8 a = *(const bf16x8*)&Gb[(mt * 16 + lr) * PS + ks * 32 + kg * 8];
                        accB[mt][0] = __builtin_amdgcn_mfma_f32_16x16x32_bf16(a, b0, accB[mt][0], 0, 0, 0);
                        accB[mt][1] = __builtin_amdgcn_mfma_f32_16x16x32_bf16(a, b1, accB[mt][1], 0, 0, 0);
                    }
                }
                __builtin_amdgcn_s_setprio(0);
                __syncthreads();
            }
            #pragma unroll
            for (int mt = 0; mt < 4; ++mt)
                #pragma unroll
                for (int nt = 0; nt < 2; ++nt) {
                    float cb = cb2[lay * CC + (nt ? c1 : c0)];
                    #pragma unroll
                    for (int r = 0; r < 4; ++r) zr[mt][nt][r] += accB[mt][nt][r] + cb;
                }
        }
    }

    // ---------- fused epilogue: masked mean + tg gather + output GEMM ------
    float* redf = (float*)ubuf;        // [8][132]
    float* zmL  = redf + 8 * 132;      // [128]
    float* znL  = zmL + 128;           // [128]
    float* oL   = znL + 128;           // [256]

    // masked mean over K from registers -> zmL
    {
        float msum = 0.f, a0v = 0.f, a1v = 0.f;
        #pragma unroll
        for (int mt = 0; mt < 4; ++mt) {
            f32x4 mk4 = *(const f32x4*)&maskArr[mt * 16 + kg * 4];
            #pragma unroll
            for (int r = 0; r < 4; ++r) {
                msum += mk4[r];
                a0v  += zr[mt][0][r] * mk4[r];
                a1v  += zr[mt][1][r] * mk4[r];
            }
        }
        a0v  += __shfl_xor(a0v, 16);  a0v  += __shfl_xor(a0v, 32);
        a1v  += __shfl_xor(a1v, 16);  a1v  += __shfl_xor(a1v, 32);
        msum += __shfl_xor(msum, 16); msum += __shfl_xor(msum, 32);
        if (kg == 0) {
            float inv = fast_rcp(fmaxf(msum, 1.0f));
            zmL[c0] = a0v * inv;
            zmL[c1] = a1v * inv;
        }
    }

    // tg ragged gather (8 rows in flight, float4 per 32-lane group)
    const int lo = seg_lo[n], hi = seg_lo[n + 1];
    {
        const int q = t & 31, g = t >> 5;
        float4 acc = {0.f, 0.f, 0.f, 0.f};
        for (int i = lo + g; i < hi; i += 8) {
            const float4* nf = (const float4*)(node_feat + (size_t)tg_idx[i] * CC);
            float4 v = nf[q];
            acc.x += v.x; acc.y += v.y; acc.z += v.z; acc.w += v.w;
        }
        *(float4*)&redf[g * 132 + q * 4] = acc;
    }
    __syncthreads();
    if (t < CC) {
        float s = 0.f;
        #pragma unroll
        for (int gg = 0; gg < 8; ++gg) s += redf[gg * 132 + t];
        float cnt = (float)(hi - lo);
        znL[t] = s / fmaxf(cnt, 1.0f) + node_feat[(size_t)seed_ids[n] * CC + t];
    }
    __syncthreads();
    // output GEMM: [zm|zn] (1x256) @ out_W (256x128)
    {
        const int c = t & 127, h = t >> 7;
        const float* src = h ? znL : zmL;
        const float* Wp  = out_W + (size_t)h * CC * 128;
        float o = 0.f;
        for (int j = 0; j < CC; ++j) o += src[j] * Wp[j * 128 + c];
        oL[h * 128 + c] = o;
    }
    __syncthreads();
    if (t < CC) outp[n * 128 + t] = oL[t] + oL[CC + t] + out_b[t];
}

extern "C" void kernel_launch(void* const* d_in, const int* in_sizes, int n_in,
                              void* d_out, int out_size, void* d_ws, size_t ws_size,
                              hipStream_t stream)
{
    const float* edge_feat  = (const float*)d_in[0];
    const float* seed_times = (const float*)d_in[1];
    const float* nbr_time   = (const float*)d_in[2];
    const float* node_feat  = (const float*)d_in[3];
    const float* time_w     = (const float*)d_in[4];
    const float* proj_W     = (const float*)d_in[5];
    const float* proj_b     = (const float*)d_in[6];
    const float* ln1_g      = (const float*)d_in[7];
    const float* ln1_b      = (const float*)d_in[8];
    const float* tW1        = (const float*)d_in[9];
    const float* tb1        = (const float*)d_in[10];
    const float* tW2        = (const float*)d_in[11];
    const float* tb2        = (const float*)d_in[12];
    const float* ln2_g      = (const float*)d_in[13];
    const float* ln2_b      = (const float*)d_in[14];
    const float* cW1        = (const float*)d_in[15];
    const float* cb1        = (const float*)d_in[16];
    const float* cW2        = (const float*)d_in[17];
    const float* cb2        = (const float*)d_in[18];
    const float* out_W      = (const float*)d_in[19];
    const float* out_b      = (const float*)d_in[20];
    const int*   nbr_nids   = (const int*)d_in[21];
    const int*   tg_idx     = (const int*)d_in[22];
    const int*   tg_seg     = (const int*)d_in[23];
    const int*   seed_ids   = (const int*)d_in[24];

    char* ws = (char*)d_ws;
    int*            seg_lo  = (int*)ws;                              //    12,292 B
    unsigned short* projWTb = (unsigned short*)(ws + 16384);         //    65,536 B
    unsigned short* tW1Tb   = (unsigned short*)(ws + 81920);         //     8,192 B
    unsigned short* tW2Tb   = (unsigned short*)(ws + 90112);         //     8,192 B
    unsigned short* cW1Tb   = (unsigned short*)(ws + 98304);         //   262,144 B
    unsigned short* cW2Tb   = (unsigned short*)(ws + 360448);        //   262,144 B

    gm_prep<<<333, 256, 0, stream>>>(cW1, cW2, proj_W, tW1, tW2, tg_seg,
                                     cW1Tb, cW2Tb, projWTb, tW1Tb, tW2Tb, seg_lo);
    gm_mixer<<<NS, 256, 0, stream>>>(edge_feat, seed_times, nbr_time, time_w,
                                     proj_b, ln1_g, ln1_b, tb1, tb2, ln2_g, ln2_b,
                                     cb1, cb2, nbr_nids,
                                     projWTb, tW1Tb, tW2Tb, cW1Tb, cW2Tb,
                                     node_feat, out_W, out_b, tg_idx, seed_ids, seg_lo,
                                     (float*)d_out);
}